// Round 1
// baseline (536.710 us; speedup 1.0000x reference)
//
#include <hip/hip_runtime.h>
#include <hip/hip_bf16.h>

// Problem constants (AriaExperts): tokens=2048, hidden=1024, inter=2048, E=8, topk=2
constexpr int T = 2048;
constexpr int H = 1024;
constexpr int I = 2048;
constexpr int N2 = 2 * I;      // fc1 weight cols (proj|gate)
constexpr int RCAP = 5120;     // padded row capacity (<= 4096 + 8*127 = 5112)
constexpr int MAXT = 40;       // max 128-row tiles (5112/128 -> 40)

// ws int-offset map
// [0,8)    counts      [8,16)   fill        [16,25)  off_pad
// [32,72)  tile_expert [96,136) tile_real_end
// [160,4256)   topk_e  [4256,8352) topk_p (float)
// [8352,13472) row_token  [13472,18592) row_scale (float)
// byte 131072: act bf16 [RCAP][I]
constexpr int WS_COUNTS = 0, WS_FILL = 8, WS_OFF = 16, WS_TEXP = 32, WS_TEND = 96;
constexpr int WS_TOPKE = 160, WS_TOPKP = 4256, WS_ROWTOK = 8352, WS_ROWSC = 13472;
constexpr size_t ACT_OFF_BYTES = 131072;

typedef __attribute__((ext_vector_type(4))) float f32x4;
typedef __attribute__((ext_vector_type(2))) float f32x2;
typedef __attribute__((ext_vector_type(8))) short s16x8;
typedef __attribute__((ext_vector_type(4))) short s16x4;

__device__ __forceinline__ short f2bf(float f) {
    unsigned u = __float_as_uint(f);
    u += 0x7FFFu + ((u >> 16) & 1u);   // round-to-nearest-even
    return (short)(u >> 16);
}

#define MFMA16(a, b, c) __builtin_amdgcn_mfma_f32_16x16x32_bf16(a, b, c, 0, 0, 0)

// ---------------- routing ----------------
__global__ void router_kernel(const float* __restrict__ logits, int* __restrict__ wsi,
                              float* __restrict__ wsf) {
    int tok = blockIdx.x * 256 + threadIdx.x;
    if (tok >= T) return;
    const float* l = logits + tok * 8;
    float v0 = -1e30f; int i0 = 0;
    #pragma unroll
    for (int i = 0; i < 8; i++) { float v = l[i]; if (v > v0) { v0 = v; i0 = i; } }
    float v1 = -1e30f; int i1 = 0;
    #pragma unroll
    for (int i = 0; i < 8; i++) { if (i == i0) continue; float v = l[i]; if (v > v1) { v1 = v; i1 = i; } }
    float ex = __expf(v1 - v0);          // <= 1, stable
    float inv = 1.f / (1.f + ex);
    wsi[WS_TOPKE + tok * 2] = i0; wsi[WS_TOPKE + tok * 2 + 1] = i1;
    wsf[WS_TOPKP + tok * 2] = inv; wsf[WS_TOPKP + tok * 2 + 1] = ex * inv;
    atomicAdd(&wsi[WS_COUNTS + i0], 1);
    atomicAdd(&wsi[WS_COUNTS + i1], 1);
}

__global__ void plan_kernel(int* __restrict__ wsi) {
    __shared__ int soff[9];
    int t = threadIdx.x;
    if (t == 0) {
        int acc = 0;
        for (int e = 0; e < 8; e++) { soff[e] = acc; acc += (wsi[WS_COUNTS + e] + 127) & ~127; }
        soff[8] = acc;
        for (int e = 0; e < 9; e++) wsi[WS_OFF + e] = soff[e];
    }
    __syncthreads();
    for (int tt = t; tt < MAXT; tt += 256) {
        int rb = tt * 128, ex = -1, en = 0;
        if (rb < soff[8]) {
            for (int e = 0; e < 8; e++)
                if (rb >= soff[e] && rb < soff[e + 1]) { ex = e; en = soff[e] + wsi[WS_COUNTS + e]; }
        }
        wsi[WS_TEXP + tt] = ex; wsi[WS_TEND + tt] = en;
    }
    float* wsf = (float*)wsi;
    for (int r = t; r < RCAP; r += 256) { wsi[WS_ROWTOK + r] = -1; wsf[WS_ROWSC + r] = 0.f; }
}

__global__ void scatter_kernel(int* __restrict__ wsi, float* __restrict__ wsf) {
    int tok = blockIdx.x * 256 + threadIdx.x;
    if (tok >= T) return;
    #pragma unroll
    for (int k = 0; k < 2; k++) {
        int e = wsi[WS_TOPKE + tok * 2 + k];
        float p = wsf[WS_TOPKP + tok * 2 + k];
        int slot = atomicAdd(&wsi[WS_FILL + e], 1);
        int r = wsi[WS_OFF + e] + slot;
        wsi[WS_ROWTOK + r] = tok;
        wsf[WS_ROWSC + r] = p;
    }
}

// ---------------- fc1 + SwiGLU ----------------
// block: 128 rows x 64 act-cols (stages 64 proj + 64 gate weight cols)
// waves 2x2; wave tile 64 rows x 32 cols; acc_p[4][2] + acc_g[4][2]
__global__ __launch_bounds__(256, 2) void fc1_kernel(
    const float* __restrict__ hs, const float* __restrict__ w1,
    const int* __restrict__ wsi, unsigned short* __restrict__ act) {
    __shared__ short Al[128 * 40];       // [row][k] padded
    __shared__ short Bl[4 * 128 * 8];    // [k/8][n(128: proj|gate)][k%8]
    const int t = threadIdx.x;
    const int ct = blockIdx.x, rt = blockIdx.y;
    const int rowb = rt * 128;
    if (rowb >= wsi[WS_OFF + 8]) return;
    const int e = wsi[WS_TEXP + rt];
    const int rend = wsi[WS_TEND + rt];
    const float* w1e = w1 + (size_t)e * H * N2;

    // A staging: thread -> row t/2, 16 floats at (t&1)*16
    const int ar = t >> 1, aseg = (t & 1) * 16;
    const int tok = wsi[WS_ROWTOK + rowb + ar];
    const float* ap = (tok >= 0) ? (hs + (size_t)tok * H + aseg) : nullptr;
    short* al = &Al[ar * 40 + aseg];
    if (!ap) {
        s16x4 z = {0, 0, 0, 0};
        #pragma unroll
        for (int i = 0; i < 4; i++) *(s16x4*)(al + i * 4) = z;
    }

    // B staging: thread -> n0=(t&63)*2, k-group g=t>>6 (k0=g*8)
    const int bn0 = (t & 63) * 2, bg = t >> 6;
    const int colg = (bn0 < 64) ? (ct * 64 + bn0) : (I + ct * 64 + (bn0 - 64));
    const float* bp = w1e + (size_t)(bg * 8) * N2 + colg;
    short* bl = &Bl[(bg * 128 + bn0) * 8];

    const int lane = t & 63, w = t >> 6, wr = w >> 1, wc = w & 1;
    const int q = lane >> 4, l16 = lane & 15;

    f32x4 zero = {0.f, 0.f, 0.f, 0.f};
    f32x4 accp[4][2], accg[4][2];
    #pragma unroll
    for (int mi = 0; mi < 4; mi++)
        #pragma unroll
        for (int ni = 0; ni < 2; ni++) { accp[mi][ni] = zero; accg[mi][ni] = zero; }

    for (int k0 = 0; k0 < H; k0 += 32) {
        if (ap) {
            #pragma unroll
            for (int i = 0; i < 4; i++) {
                f32x4 v = *(const f32x4*)(ap + k0 + i * 4);
                s16x4 s = {f2bf(v[0]), f2bf(v[1]), f2bf(v[2]), f2bf(v[3])};
                *(s16x4*)(al + i * 4) = s;
            }
        }
        f32x2 v[8];
        #pragma unroll
        for (int i = 0; i < 8; i++) v[i] = *(const f32x2*)(bp + (size_t)(k0 + i) * N2);
        s16x8 s0, s1;
        #pragma unroll
        for (int i = 0; i < 8; i++) { s0[i] = f2bf(v[i][0]); s1[i] = f2bf(v[i][1]); }
        *(s16x8*)bl = s0;
        *(s16x8*)(bl + 8) = s1;
        __syncthreads();

        s16x8 af[4], bpf[2], bgf[2];
        const int koff = q * 8;
        #pragma unroll
        for (int mi = 0; mi < 4; mi++)
            af[mi] = *(const s16x8*)&Al[(wr * 64 + mi * 16 + l16) * 40 + koff];
        #pragma unroll
        for (int ni = 0; ni < 2; ni++) {
            int nr = wc * 32 + ni * 16 + l16;
            bpf[ni] = *(const s16x8*)&Bl[(q * 128 + nr) * 8];
            bgf[ni] = *(const s16x8*)&Bl[(q * 128 + 64 + nr) * 8];
        }
        #pragma unroll
        for (int mi = 0; mi < 4; mi++)
            #pragma unroll
            for (int ni = 0; ni < 2; ni++) {
                accp[mi][ni] = MFMA16(af[mi], bpf[ni], accp[mi][ni]);
                accg[mi][ni] = MFMA16(af[mi], bgf[ni], accg[mi][ni]);
            }
        __syncthreads();
    }

    // epilogue: SwiGLU, write bf16 act (pad rows -> 0)
    #pragma unroll
    for (int mi = 0; mi < 4; mi++)
        #pragma unroll
        for (int r = 0; r < 4; r++) {
            int row = rowb + wr * 64 + mi * 16 + q * 4 + r;
            bool real = row < rend;
            #pragma unroll
            for (int ni = 0; ni < 2; ni++) {
                int col = ct * 64 + wc * 32 + ni * 16 + l16;
                float p = accp[mi][ni][r], g = accg[mi][ni][r];
                float val = real ? (p * g / (1.f + __expf(-p))) : 0.f;
                act[(size_t)row * I + col] = (unsigned short)f2bf(val);
            }
        }
}

// ---------------- fc2 + scaled scatter-add ----------------
// block: 128 rows x 64 out-cols; waves 2x2; wave 64x32; acc[4][2]
__global__ __launch_bounds__(256, 2) void fc2_kernel(
    const unsigned short* __restrict__ act, const float* __restrict__ w2,
    const int* __restrict__ wsi, const float* __restrict__ wsf,
    float* __restrict__ out) {
    __shared__ short Al[128 * 40];
    __shared__ short Bl[4 * 64 * 8];
    const int t = threadIdx.x;
    const int ht = blockIdx.x, rt = blockIdx.y;
    const int rowb = rt * 128;
    if (rowb >= wsi[WS_OFF + 8]) return;
    const int e = wsi[WS_TEXP + rt];
    const float* w2e = w2 + (size_t)e * I * H;

    const int ar = t >> 1, aseg = (t & 1) * 16;
    const unsigned short* ap = act + (size_t)(rowb + ar) * I + aseg;
    short* al = &Al[ar * 40 + aseg];

    const int bn0 = (t & 31) * 2, bg = (t >> 5) & 3;
    const float* bp = w2e + (size_t)(bg * 8) * H + ht * 64 + bn0;
    short* bl = &Bl[(bg * 64 + bn0) * 8];
    const bool bact = (t < 128);

    const int lane = t & 63, w = t >> 6, wr = w >> 1, wc = w & 1;
    const int q = lane >> 4, l16 = lane & 15;

    f32x4 zero = {0.f, 0.f, 0.f, 0.f};
    f32x4 acc[4][2];
    #pragma unroll
    for (int mi = 0; mi < 4; mi++)
        #pragma unroll
        for (int ni = 0; ni < 2; ni++) acc[mi][ni] = zero;

    for (int k0 = 0; k0 < I; k0 += 32) {
        *(s16x8*)al = *(const s16x8*)(ap + k0);
        *(s16x8*)(al + 8) = *(const s16x8*)(ap + k0 + 8);
        if (bact) {
            f32x2 v[8];
            #pragma unroll
            for (int i = 0; i < 8; i++) v[i] = *(const f32x2*)(bp + (size_t)(k0 + i) * H);
            s16x8 s0, s1;
            #pragma unroll
            for (int i = 0; i < 8; i++) { s0[i] = f2bf(v[i][0]); s1[i] = f2bf(v[i][1]); }
            *(s16x8*)bl = s0;
            *(s16x8*)(bl + 8) = s1;
        }
        __syncthreads();

        s16x8 af[4], bf[2];
        const int koff = q * 8;
        #pragma unroll
        for (int mi = 0; mi < 4; mi++)
            af[mi] = *(const s16x8*)&Al[(wr * 64 + mi * 16 + l16) * 40 + koff];
        #pragma unroll
        for (int ni = 0; ni < 2; ni++) {
            int nr = wc * 32 + ni * 16 + l16;
            bf[ni] = *(const s16x8*)&Bl[(q * 64 + nr) * 8];
        }
        #pragma unroll
        for (int mi = 0; mi < 4; mi++)
            #pragma unroll
            for (int ni = 0; ni < 2; ni++)
                acc[mi][ni] = MFMA16(af[mi], bf[ni], acc[mi][ni]);
        __syncthreads();
    }

    #pragma unroll
    for (int mi = 0; mi < 4; mi++)
        #pragma unroll
        for (int r = 0; r < 4; r++) {
            int row = rowb + wr * 64 + mi * 16 + q * 4 + r;
            int tok = wsi[WS_ROWTOK + row];
            if (tok < 0) continue;
            float sc = wsf[WS_ROWSC + row];
            #pragma unroll
            for (int ni = 0; ni < 2; ni++) {
                int col = ht * 64 + wc * 32 + ni * 16 + l16;
                atomicAdd(&out[(size_t)tok * H + col], acc[mi][ni][r] * sc);
            }
        }
}

extern "C" void kernel_launch(void* const* d_in, const int* in_sizes, int n_in,
                              void* d_out, int out_size, void* d_ws, size_t ws_size,
                              hipStream_t stream) {
    const float* hs     = (const float*)d_in[0];
    const float* logits = (const float*)d_in[1];
    const float* w1     = (const float*)d_in[2];
    const float* w2     = (const float*)d_in[3];
    float* out = (float*)d_out;
    int* wsi = (int*)d_ws;
    float* wsf = (float*)d_ws;
    unsigned short* act = (unsigned short*)((char*)d_ws + ACT_OFF_BYTES);

    hipMemsetAsync(d_ws, 0, 128, stream);                             // counts/fill
    hipMemsetAsync(d_out, 0, (size_t)out_size * sizeof(float), stream);

    router_kernel<<<(T + 255) / 256, 256, 0, stream>>>(logits, wsi, wsf);
    plan_kernel<<<1, 256, 0, stream>>>(wsi);
    scatter_kernel<<<(T + 255) / 256, 256, 0, stream>>>(wsi, wsf);
    fc1_kernel<<<dim3(I / 64, MAXT), 256, 0, stream>>>(hs, w1, wsi, act);
    fc2_kernel<<<dim3(H / 64, MAXT), 256, 0, stream>>>(act, w2, wsi, wsf, out);
}

// Round 2
// 449.174 us; speedup vs baseline: 1.1949x; 1.1949x over previous
//
#include <hip/hip_runtime.h>
#include <hip/hip_bf16.h>

// Problem constants (AriaExperts): tokens=2048, hidden=1024, inter=2048, E=8, topk=2
constexpr int T = 2048;
constexpr int H = 1024;
constexpr int I = 2048;
constexpr int N2 = 2 * I;      // fc1 weight cols (proj|gate)
constexpr int RCAP = 5120;     // padded row capacity (<= 4096 + 8*127 = 5112)
constexpr int MAXT = 40;       // max 128-row tiles

// ws int-offset map (ints)
constexpr int WS_COUNTS = 0, WS_FILL = 8, WS_OFF = 16, WS_TEXP = 32, WS_TEND = 96;
constexpr int WS_TOPKE = 160, WS_TOPKP = 4256, WS_ROWTOK = 8352, WS_ROWSC = 13472;
// ws byte offsets
constexpr size_t WSB_ZROW = 114688;      // bf16 zero row, H elements (2 KB)
constexpr size_t WSB_HSB  = 131072;      // bf16 hidden_states [T][H] (4 MB)
constexpr size_t WSB_ACT  = 8u << 20;    // bf16 act [RCAP][I] (20 MB)
constexpr size_t WSB_PW1  = 32u << 20;   // packed bf16 w1 (64 MB)
constexpr size_t WSB_PW2  = 96u << 20;   // packed bf16 w2 (32 MB) -> needs 128 MB ws

typedef __attribute__((ext_vector_type(4))) float f32x4;
typedef __attribute__((ext_vector_type(8))) short s16x8;

__device__ __forceinline__ short f2bf(float f) {
    unsigned u = __float_as_uint(f);
    u += 0x7FFFu + ((u >> 16) & 1u);   // round-to-nearest-even
    return (short)(u >> 16);
}

#define MFMA16(a, b, c) __builtin_amdgcn_mfma_f32_16x16x32_bf16(a, b, c, 0, 0, 0)

__device__ __forceinline__ void gl2lds16(const void* g, void* l) {
    __builtin_amdgcn_global_load_lds(
        (const __attribute__((address_space(1))) void*)g,
        (__attribute__((address_space(3))) void*)l, 16, 0, 0);
}

// ---------------- routing ----------------
__global__ void router_kernel(const float* __restrict__ logits, int* __restrict__ wsi,
                              float* __restrict__ wsf) {
    int tok = blockIdx.x * 256 + threadIdx.x;
    if (tok >= T) return;
    const float* l = logits + tok * 8;
    float v0 = -1e30f; int i0 = 0;
    #pragma unroll
    for (int i = 0; i < 8; i++) { float v = l[i]; if (v > v0) { v0 = v; i0 = i; } }
    float v1 = -1e30f; int i1 = 0;
    #pragma unroll
    for (int i = 0; i < 8; i++) { if (i == i0) continue; float v = l[i]; if (v > v1) { v1 = v; i1 = i; } }
    float ex = __expf(v1 - v0);
    float inv = 1.f / (1.f + ex);
    wsi[WS_TOPKE + tok * 2] = i0; wsi[WS_TOPKE + tok * 2 + 1] = i1;
    wsf[WS_TOPKP + tok * 2] = inv; wsf[WS_TOPKP + tok * 2 + 1] = ex * inv;
    atomicAdd(&wsi[WS_COUNTS + i0], 1);
    atomicAdd(&wsi[WS_COUNTS + i1], 1);
}

__global__ void plan_kernel(int* __restrict__ wsi) {
    __shared__ int soff[9];
    int t = threadIdx.x;
    if (t == 0) {
        int acc = 0;
        for (int e = 0; e < 8; e++) { soff[e] = acc; acc += (wsi[WS_COUNTS + e] + 127) & ~127; }
        soff[8] = acc;
        for (int e = 0; e < 9; e++) wsi[WS_OFF + e] = soff[e];
    }
    __syncthreads();
    for (int tt = t; tt < MAXT; tt += 256) {
        int rb = tt * 128, ex = -1, en = 0;
        if (rb < soff[8]) {
            for (int e = 0; e < 8; e++)
                if (rb >= soff[e] && rb < soff[e + 1]) { ex = e; en = soff[e] + wsi[WS_COUNTS + e]; }
        }
        wsi[WS_TEXP + tt] = ex; wsi[WS_TEND + tt] = en;
    }
    float* wsf = (float*)wsi;
    for (int r = t; r < RCAP; r += 256) { wsi[WS_ROWTOK + r] = -1; wsf[WS_ROWSC + r] = 0.f; }
    unsigned short* zr = (unsigned short*)((char*)wsi + WSB_ZROW);
    for (int i = t; i < H; i += 256) zr[i] = 0;
}

__global__ void scatter_kernel(int* __restrict__ wsi, float* __restrict__ wsf) {
    int tok = blockIdx.x * 256 + threadIdx.x;
    if (tok >= T) return;
    #pragma unroll
    for (int k = 0; k < 2; k++) {
        int e = wsi[WS_TOPKE + tok * 2 + k];
        float p = wsf[WS_TOPKP + tok * 2 + k];
        int slot = atomicAdd(&wsi[WS_FILL + e], 1);
        int r = wsi[WS_OFF + e] + slot;
        wsi[WS_ROWTOK + r] = tok;
        wsf[WS_ROWSC + r] = p;
    }
}

// ---------------- fp32 -> bf16 conversions / weight packing ----------------
__global__ __launch_bounds__(256) void hs2bf_kernel(const float* __restrict__ hs,
                                                    unsigned short* __restrict__ hsb) {
    int i = (blockIdx.x * 256 + threadIdx.x) * 8;
    f32x4 a = *(const f32x4*)(hs + i);
    f32x4 b = *(const f32x4*)(hs + i + 4);
    s16x8 s = {f2bf(a[0]), f2bf(a[1]), f2bf(a[2]), f2bf(a[3]),
               f2bf(b[0]), f2bf(b[1]), f2bf(b[2]), f2bf(b[3])};
    *(s16x8*)(hsb + i) = s;
}

// pw1 layout: [e][ct:16][k0i:32] x contiguous 8192 el = [pg:2][kg:4][n:128][kk:8]
__global__ __launch_bounds__(256) void pack_w1_kernel(const float* __restrict__ w1,
                                                      unsigned short* __restrict__ pw1) {
    int b = blockIdx.x;                 // (e*16+ct)*32 + k0i
    int k0i = b & 31, ct = (b >> 5) & 15, e = b >> 9;
    const float* src = w1 + (size_t)e * H * N2;
    unsigned short* dst = pw1 + (size_t)b * 8192;
    int t = threadIdx.x;
    #pragma unroll
    for (int j = 0; j < 4; j++) {
        int g = t + j * 256;
        int pg = g >> 9, kg = (g >> 7) & 3, n = g & 127;
        int col = pg * I + ct * 128 + n;
        int kbase = k0i * 32 + kg * 8;
        const float* sp = src + (size_t)kbase * N2 + col;
        s16x8 s;
        #pragma unroll
        for (int kk = 0; kk < 8; kk++) s[kk] = f2bf(sp[(size_t)kk * N2]);
        *(s16x8*)(dst + g * 8) = s;
    }
}

// pw2 layout: [e][ht:8][k0i:64] x contiguous 4096 el = [kg:4][n:128][kk:8]
__global__ __launch_bounds__(256) void pack_w2_kernel(const float* __restrict__ w2,
                                                      unsigned short* __restrict__ pw2) {
    int b = blockIdx.x;                 // (e*8+ht)*64 + k0i
    int k0i = b & 63, ht = (b >> 6) & 7, e = b >> 9;
    const float* src = w2 + (size_t)e * I * H;
    unsigned short* dst = pw2 + (size_t)b * 4096;
    int t = threadIdx.x;
    #pragma unroll
    for (int j = 0; j < 2; j++) {
        int g = t + j * 256;
        int kg = g >> 7, n = g & 127;
        int col = ht * 128 + n;
        int kbase = k0i * 32 + kg * 8;
        const float* sp = src + (size_t)kbase * H + col;
        s16x8 s;
        #pragma unroll
        for (int kk = 0; kk < 8; kk++) s[kk] = f2bf(sp[(size_t)kk * H]);
        *(s16x8*)(dst + g * 8) = s;
    }
}

// ---------------- fc1 + SwiGLU: 128 rows x 128 out-cols, BK=32 ----------------
__global__ __launch_bounds__(256, 2) void fc1_kernel(
    const unsigned short* __restrict__ hsb, const unsigned short* __restrict__ pw1,
    const int* __restrict__ wsi, const unsigned short* __restrict__ zrow,
    unsigned short* __restrict__ act) {
    __shared__ __align__(16) unsigned short Al[512 * 8];    // [kg:4][m:128][8]
    __shared__ __align__(16) unsigned short Bl[1024 * 8];   // [pg:2][kg:4][n:128][8]
    const int t = threadIdx.x;
    const int ct = blockIdx.x, rt = blockIdx.y;
    const int rowb = rt * 128;
    if (rowb >= wsi[WS_OFF + 8]) return;
    const int e = wsi[WS_TEXP + rt];
    const unsigned short* pb = pw1 + (size_t)(e * 16 + ct) * 32 * 8192;

    const int m = t & 127;
    const int kga = t >> 7;            // 0/1; second chunk uses kga+2
    const int tok = wsi[WS_ROWTOK + rowb + m];
    const unsigned short* rp = (tok >= 0) ? (hsb + (size_t)tok * H) : zrow;

    const int lane = t & 63, w = t >> 6, wr = w >> 1, wc = w & 1;
    const int q = lane >> 4, l16 = lane & 15;

    f32x4 zero = {0.f, 0.f, 0.f, 0.f};
    f32x4 accp[4][4], accg[4][4];
    #pragma unroll
    for (int mi = 0; mi < 4; mi++)
        #pragma unroll
        for (int ni = 0; ni < 4; ni++) { accp[mi][ni] = zero; accg[mi][ni] = zero; }

    for (int k0i = 0; k0i < 32; k0i++) {
        const int k0 = k0i * 32;
        gl2lds16(rp + k0 + kga * 8, &Al[t * 8]);
        gl2lds16(rp + k0 + (kga + 2) * 8, &Al[(t + 256) * 8]);
        const unsigned short* ps = pb + (size_t)k0i * 8192;
        #pragma unroll
        for (int j = 0; j < 4; j++)
            gl2lds16(ps + (t + j * 256) * 8, &Bl[(t + j * 256) * 8]);
        __syncthreads();

        s16x8 af[4], bpf[4], bgf[4];
        #pragma unroll
        for (int mi = 0; mi < 4; mi++)
            af[mi] = *(const s16x8*)&Al[(q * 128 + wr * 64 + mi * 16 + l16) * 8];
        #pragma unroll
        for (int ni = 0; ni < 4; ni++) {
            int col = wc * 64 + ni * 16 + l16;
            bpf[ni] = *(const s16x8*)&Bl[(q * 128 + col) * 8];
            bgf[ni] = *(const s16x8*)&Bl[(512 + q * 128 + col) * 8];
        }
        #pragma unroll
        for (int mi = 0; mi < 4; mi++)
            #pragma unroll
            for (int ni = 0; ni < 4; ni++) {
                accp[mi][ni] = MFMA16(af[mi], bpf[ni], accp[mi][ni]);
                accg[mi][ni] = MFMA16(af[mi], bgf[ni], accg[mi][ni]);
            }
        __syncthreads();
    }

    // epilogue: SwiGLU -> bf16 act (pad rows computed on zero rows -> exact 0)
    #pragma unroll
    for (int mi = 0; mi < 4; mi++)
        #pragma unroll
        for (int r = 0; r < 4; r++) {
            int row = rowb + wr * 64 + mi * 16 + q * 4 + r;
            #pragma unroll
            for (int ni = 0; ni < 4; ni++) {
                int col = ct * 128 + wc * 64 + ni * 16 + l16;
                float p = accp[mi][ni][r], g = accg[mi][ni][r];
                float val = p * g / (1.f + __expf(-p));
                act[(size_t)row * I + col] = (unsigned short)f2bf(val);
            }
        }
}

// ---------------- fc2 + scaled scatter-add: 128 rows x 128 out-cols ----------------
__global__ __launch_bounds__(256, 2) void fc2_kernel(
    const unsigned short* __restrict__ act, const unsigned short* __restrict__ pw2,
    const int* __restrict__ wsi, const float* __restrict__ wsf,
    float* __restrict__ out) {
    __shared__ __align__(16) unsigned short Al[512 * 8];    // [kg:4][m:128][8]
    __shared__ __align__(16) unsigned short Bl[512 * 8];    // [kg:4][n:128][8]
    const int t = threadIdx.x;
    const int ht = blockIdx.x, rt = blockIdx.y;
    const int rowb = rt * 128;
    if (rowb >= wsi[WS_OFF + 8]) return;
    const int e = wsi[WS_TEXP + rt];
    const unsigned short* pb = pw2 + (size_t)(e * 8 + ht) * 64 * 4096;

    const int m = t & 127;
    const int kga = t >> 7;
    const unsigned short* rp = act + (size_t)(rowb + m) * I;

    const int lane = t & 63, w = t >> 6, wr = w >> 1, wc = w & 1;
    const int q = lane >> 4, l16 = lane & 15;

    f32x4 zero = {0.f, 0.f, 0.f, 0.f};
    f32x4 acc[4][4];
    #pragma unroll
    for (int mi = 0; mi < 4; mi++)
        #pragma unroll
        for (int ni = 0; ni < 4; ni++) acc[mi][ni] = zero;

    for (int k0i = 0; k0i < 64; k0i++) {
        const int k0 = k0i * 32;
        gl2lds16(rp + k0 + kga * 8, &Al[t * 8]);
        gl2lds16(rp + k0 + (kga + 2) * 8, &Al[(t + 256) * 8]);
        const unsigned short* ps = pb + (size_t)k0i * 4096;
        gl2lds16(ps + t * 8, &Bl[t * 8]);
        gl2lds16(ps + (t + 256) * 8, &Bl[(t + 256) * 8]);
        __syncthreads();

        s16x8 af[4], bf[4];
        #pragma unroll
        for (int mi = 0; mi < 4; mi++)
            af[mi] = *(const s16x8*)&Al[(q * 128 + wr * 64 + mi * 16 + l16) * 8];
        #pragma unroll
        for (int ni = 0; ni < 4; ni++)
            bf[ni] = *(const s16x8*)&Bl[(q * 128 + wc * 64 + ni * 16 + l16) * 8];
        #pragma unroll
        for (int mi = 0; mi < 4; mi++)
            #pragma unroll
            for (int ni = 0; ni < 4; ni++)
                acc[mi][ni] = MFMA16(af[mi], bf[ni], acc[mi][ni]);
        __syncthreads();
    }

    #pragma unroll
    for (int mi = 0; mi < 4; mi++)
        #pragma unroll
        for (int r = 0; r < 4; r++) {
            int row = rowb + wr * 64 + mi * 16 + q * 4 + r;
            int tok = wsi[WS_ROWTOK + row];
            if (tok < 0) continue;
            float sc = wsf[WS_ROWSC + row];
            #pragma unroll
            for (int ni = 0; ni < 4; ni++) {
                int col = ht * 128 + wc * 64 + ni * 16 + l16;
                atomicAdd(&out[(size_t)tok * H + col], acc[mi][ni][r] * sc);
            }
        }
}

extern "C" void kernel_launch(void* const* d_in, const int* in_sizes, int n_in,
                              void* d_out, int out_size, void* d_ws, size_t ws_size,
                              hipStream_t stream) {
    const float* hs     = (const float*)d_in[0];
    const float* logits = (const float*)d_in[1];
    const float* w1     = (const float*)d_in[2];
    const float* w2     = (const float*)d_in[3];
    float* out = (float*)d_out;
    int* wsi = (int*)d_ws;
    float* wsf = (float*)d_ws;
    unsigned short* zrow = (unsigned short*)((char*)d_ws + WSB_ZROW);
    unsigned short* hsb  = (unsigned short*)((char*)d_ws + WSB_HSB);
    unsigned short* act  = (unsigned short*)((char*)d_ws + WSB_ACT);
    unsigned short* pw1  = (unsigned short*)((char*)d_ws + WSB_PW1);
    unsigned short* pw2  = (unsigned short*)((char*)d_ws + WSB_PW2);

    hipMemsetAsync(d_ws, 0, 128, stream);
    hipMemsetAsync(d_out, 0, (size_t)out_size * sizeof(float), stream);

    router_kernel<<<(T + 255) / 256, 256, 0, stream>>>(logits, wsi, wsf);
    plan_kernel<<<1, 256, 0, stream>>>(wsi);
    scatter_kernel<<<(T + 255) / 256, 256, 0, stream>>>(wsi, wsf);
    hs2bf_kernel<<<T * H / 2048, 256, 0, stream>>>(hs, hsb);
    pack_w1_kernel<<<8 * 16 * 32, 256, 0, stream>>>(w1, pw1);
    pack_w2_kernel<<<8 * 8 * 64, 256, 0, stream>>>(w2, pw2);
    fc1_kernel<<<dim3(16, MAXT), 256, 0, stream>>>(hsb, pw1, wsi, zrow, act);
    fc2_kernel<<<dim3(8, MAXT), 256, 0, stream>>>(act, pw2, wsi, wsf, out);
}

// Round 3
// 418.281 us; speedup vs baseline: 1.2831x; 1.0739x over previous
//
#include <hip/hip_runtime.h>
#include <hip/hip_bf16.h>

// Problem constants (AriaExperts): tokens=2048, hidden=1024, inter=2048, E=8, topk=2
constexpr int T = 2048;
constexpr int H = 1024;
constexpr int I = 2048;
constexpr int N2 = 2 * I;      // fc1 weight cols (proj|gate)
constexpr int RCAP = 5120;     // padded row capacity
constexpr int MAXT = 40;       // max 128-row tiles

// ws int-offset map (ints)
constexpr int WS_COUNTS = 0, WS_FILL = 8, WS_OFF = 16, WS_TEXP = 32, WS_TEND = 96;
constexpr int WS_TOPKE = 160, WS_TOPKP = 4256, WS_ROWTOK = 8352, WS_ROWSC = 13472;
// ws byte offsets
constexpr size_t WSB_ZROW = 114688;      // bf16 zero row, H elements
constexpr size_t WSB_HSB  = 131072;      // bf16 hidden_states [T][H] (4 MB)
constexpr size_t WSB_ACT  = 8u << 20;    // bf16 act [RCAP][I] (20 MB)
constexpr size_t WSB_PW1  = 32u << 20;   // packed bf16 w1 (64 MB)
constexpr size_t WSB_PW2  = 96u << 20;   // packed bf16 w2 (32 MB) -> 128 MB ws

constexpr int FC1_BLKS = 32 * MAXT;      // 1280
constexpr int PW2_BLKS = 4096;
constexpr int PW1_BLKS = 8192;
constexpr int HSB_BLKS = T * H / 2048;   // 1024

typedef __attribute__((ext_vector_type(4))) float f32x4;
typedef __attribute__((ext_vector_type(8))) short s16x8;

__device__ __forceinline__ short f2bf(float f) {
    unsigned u = __float_as_uint(f);
    u += 0x7FFFu + ((u >> 16) & 1u);   // round-to-nearest-even
    return (short)(u >> 16);
}

#define MFMA16(a, b, c) __builtin_amdgcn_mfma_f32_16x16x32_bf16(a, b, c, 0, 0, 0)

__device__ __forceinline__ void gl2lds16(const void* g, void* l) {
    __builtin_amdgcn_global_load_lds(
        (const __attribute__((address_space(1))) void*)g,
        (__attribute__((address_space(3))) void*)l, 16, 0, 0);
}

// ---------------- routing ----------------
__global__ void router_kernel(const float* __restrict__ logits, int* __restrict__ wsi,
                              float* __restrict__ wsf) {
    int tok = blockIdx.x * 256 + threadIdx.x;
    if (tok >= T) return;
    const float* l = logits + tok * 8;
    float v0 = -1e30f; int i0 = 0;
    #pragma unroll
    for (int i = 0; i < 8; i++) { float v = l[i]; if (v > v0) { v0 = v; i0 = i; } }
    float v1 = -1e30f; int i1 = 0;
    #pragma unroll
    for (int i = 0; i < 8; i++) { if (i == i0) continue; float v = l[i]; if (v > v1) { v1 = v; i1 = i; } }
    float ex = __expf(v1 - v0);
    float inv = 1.f / (1.f + ex);
    wsi[WS_TOPKE + tok * 2] = i0; wsi[WS_TOPKE + tok * 2 + 1] = i1;
    wsf[WS_TOPKP + tok * 2] = inv; wsf[WS_TOPKP + tok * 2 + 1] = ex * inv;
    atomicAdd(&wsi[WS_COUNTS + i0], 1);
    atomicAdd(&wsi[WS_COUNTS + i1], 1);
}

__global__ void plan_kernel(int* __restrict__ wsi) {
    __shared__ int soff[9];
    int t = threadIdx.x;
    if (t == 0) {
        int acc = 0;
        for (int e = 0; e < 8; e++) { soff[e] = acc; acc += (wsi[WS_COUNTS + e] + 127) & ~127; }
        soff[8] = acc;
        for (int e = 0; e < 9; e++) wsi[WS_OFF + e] = soff[e];
    }
    __syncthreads();
    for (int tt = t; tt < MAXT; tt += 256) {
        int rb = tt * 128, ex = -1, en = 0;
        if (rb < soff[8]) {
            for (int e = 0; e < 8; e++)
                if (rb >= soff[e] && rb < soff[e + 1]) { ex = e; en = soff[e] + wsi[WS_COUNTS + e]; }
        }
        wsi[WS_TEXP + tt] = ex; wsi[WS_TEND + tt] = en;
    }
    float* wsf = (float*)wsi;
    for (int r = t; r < RCAP; r += 256) { wsi[WS_ROWTOK + r] = -1; wsf[WS_ROWSC + r] = 0.f; }
    unsigned short* zr = (unsigned short*)((char*)wsi + WSB_ZROW);
    for (int i = t; i < H; i += 256) zr[i] = 0;
}

__global__ void scatter_kernel(int* __restrict__ wsi, float* __restrict__ wsf) {
    int tok = blockIdx.x * 256 + threadIdx.x;
    if (tok >= T) return;
    #pragma unroll
    for (int k = 0; k < 2; k++) {
        int e = wsi[WS_TOPKE + tok * 2 + k];
        float p = wsf[WS_TOPKP + tok * 2 + k];
        int slot = atomicAdd(&wsi[WS_FILL + e], 1);
        int r = wsi[WS_OFF + e] + slot;
        wsi[WS_ROWTOK + r] = tok;
        wsf[WS_ROWSC + r] = p;
    }
}

// ---------------- prep: pack_w1 (interleaved 32p|32g) + hs2bf, fused ----------------
// pw1 layout: [e][ct:32][k0i:32] x 4096 el = [kg:4][n:128][kk:8]
// tile col n: sub=n>>5, within=n&31; global col = (sub&1 ? I : 0) + ct*64 + (sub>>1)*32 + within
__global__ __launch_bounds__(256) void prep_kernel(
    const float* __restrict__ w1, unsigned short* __restrict__ pw1,
    const float* __restrict__ hs, unsigned short* __restrict__ hsb) {
    const int t = threadIdx.x;
    if (blockIdx.x < PW1_BLKS) {
        int b = blockIdx.x;                 // ((e*32+ct)*32)+k0i
        int k0i = b & 31, ct = (b >> 5) & 31, e = b >> 10;
        const float* src = w1 + (size_t)e * H * N2;
        unsigned short* dst = pw1 + (size_t)b * 4096;
        #pragma unroll
        for (int j = 0; j < 2; j++) {
            int g = t + j * 256;            // [0,512)
            int kg = g >> 7, n = g & 127;
            int sub = n >> 5, within = n & 31;
            int col = ((sub & 1) ? I : 0) + ct * 64 + (sub >> 1) * 32 + within;
            int kbase = k0i * 32 + kg * 8;
            const float* sp = src + (size_t)kbase * N2 + col;
            s16x8 s;
            #pragma unroll
            for (int kk = 0; kk < 8; kk++) s[kk] = f2bf(sp[(size_t)kk * N2]);
            *(s16x8*)(dst + g * 8) = s;
        }
    } else {
        int i = ((blockIdx.x - PW1_BLKS) * 256 + t) * 8;
        f32x4 a = *(const f32x4*)(hs + i);
        f32x4 b = *(const f32x4*)(hs + i + 4);
        s16x8 s = {f2bf(a[0]), f2bf(a[1]), f2bf(a[2]), f2bf(a[3]),
                   f2bf(b[0]), f2bf(b[1]), f2bf(b[2]), f2bf(b[3])};
        *(s16x8*)(hsb + i) = s;
    }
}

// ---------------- fc1 (128x128, BK=32) + SwiGLU, fused with pack_w2 ----------------
// pw2 layout: [e][ht:8][k0i:64] x 4096 el = [kg:4][n:128][kk:8]
__global__ __launch_bounds__(256, 2) void fc1_packw2_kernel(
    const unsigned short* __restrict__ hsb, const unsigned short* __restrict__ pw1,
    const int* __restrict__ wsi, const unsigned short* __restrict__ zrow,
    unsigned short* __restrict__ act,
    const float* __restrict__ w2, unsigned short* __restrict__ pw2) {
    __shared__ __align__(16) unsigned short Al[512 * 8];    // [kg:4][m:128][8]
    __shared__ __align__(16) unsigned short Bl[512 * 8];    // [kg:4][n:128][8]
    const int t = threadIdx.x;

    if (blockIdx.x >= FC1_BLKS) {
        // ---- pack_w2 role ----
        int b = blockIdx.x - FC1_BLKS;      // ((e*8+ht)*64)+k0i
        int k0i = b & 63, ht = (b >> 6) & 7, e = b >> 9;
        const float* src = w2 + (size_t)e * I * H;
        unsigned short* dst = pw2 + (size_t)b * 4096;
        #pragma unroll
        for (int j = 0; j < 2; j++) {
            int g = t + j * 256;
            int kg = g >> 7, n = g & 127;
            int col = ht * 128 + n;
            int kbase = k0i * 32 + kg * 8;
            const float* sp = src + (size_t)kbase * H + col;
            s16x8 s;
            #pragma unroll
            for (int kk = 0; kk < 8; kk++) s[kk] = f2bf(sp[(size_t)kk * H]);
            *(s16x8*)(dst + g * 8) = s;
        }
        return;
    }

    // ---- fc1 role ----
    const int ct = blockIdx.x & 31, rt = blockIdx.x >> 5;
    const int rowb = rt * 128;
    if (rowb >= wsi[WS_OFF + 8]) return;
    const int e = wsi[WS_TEXP + rt];
    const unsigned short* pb = pw1 + (size_t)((e * 32 + ct) * 32) * 4096;

    const int m = t & 127;
    const int tok = wsi[WS_ROWTOK + rowb + m];
    const unsigned short* rp = (tok >= 0) ? (hsb + (size_t)tok * H) : zrow;
    const int kga = t >> 7;                 // 0/1; second A chunk uses kga+2

    const int lane = t & 63, w = t >> 6, wr = w >> 1, wc = w & 1;
    const int q = lane >> 4, l16 = lane & 15;

    f32x4 zero = {0.f, 0.f, 0.f, 0.f};
    f32x4 acc[4][4];
    #pragma unroll
    for (int mi = 0; mi < 4; mi++)
        #pragma unroll
        for (int ni = 0; ni < 4; ni++) acc[mi][ni] = zero;

    for (int k0i = 0; k0i < 32; k0i++) {
        const int k0 = k0i * 32;
        gl2lds16(rp + k0 + kga * 8, &Al[t * 8]);
        gl2lds16(rp + k0 + (kga + 2) * 8, &Al[(t + 256) * 8]);
        const unsigned short* ps = pb + (size_t)k0i * 4096;
        gl2lds16(ps + t * 8, &Bl[t * 8]);
        gl2lds16(ps + (t + 256) * 8, &Bl[(t + 256) * 8]);
        __syncthreads();

        s16x8 af[4], bf[4];
        #pragma unroll
        for (int mi = 0; mi < 4; mi++)
            af[mi] = *(const s16x8*)&Al[(q * 128 + wr * 64 + mi * 16 + l16) * 8];
        #pragma unroll
        for (int ni = 0; ni < 4; ni++)
            bf[ni] = *(const s16x8*)&Bl[(q * 128 + wc * 64 + ni * 16 + l16) * 8];
        #pragma unroll
        for (int mi = 0; mi < 4; mi++)
            #pragma unroll
            for (int ni = 0; ni < 4; ni++)
                acc[mi][ni] = MFMA16(af[mi], bf[ni], acc[mi][ni]);
        __syncthreads();
    }

    // epilogue: wave cols = 32 proj + 32 gate (ni 0,1 = proj; ni 2,3 = matching gate)
    #pragma unroll
    for (int mi = 0; mi < 4; mi++)
        #pragma unroll
        for (int r = 0; r < 4; r++) {
            int row = rowb + wr * 64 + mi * 16 + q * 4 + r;
            #pragma unroll
            for (int ni = 0; ni < 2; ni++) {
                int col = ct * 64 + wc * 32 + ni * 16 + l16;
                float p = acc[mi][ni][r], g = acc[mi][ni + 2][r];
                float val = p * g / (1.f + __expf(-p));
                act[(size_t)row * I + col] = (unsigned short)f2bf(val);
            }
        }
}

// ---------------- fc2 (128x128, BK=32, K split x2) + scaled scatter-add ----------------
__global__ __launch_bounds__(256, 2) void fc2_kernel(
    const unsigned short* __restrict__ act, const unsigned short* __restrict__ pw2,
    const int* __restrict__ wsi, const float* __restrict__ wsf,
    float* __restrict__ out) {
    __shared__ __align__(16) unsigned short Al[512 * 8];
    __shared__ __align__(16) unsigned short Bl[512 * 8];
    const int t = threadIdx.x;
    const int ht = blockIdx.x, rt = blockIdx.y, ks = blockIdx.z;
    const int rowb = rt * 128;
    if (rowb >= wsi[WS_OFF + 8]) return;
    const int e = wsi[WS_TEXP + rt];
    const unsigned short* pb = pw2 + (size_t)((e * 8 + ht) * 64) * 4096;

    const int m = t & 127;
    const unsigned short* rp = act + (size_t)(rowb + m) * I;
    const int kga = t >> 7;

    const int lane = t & 63, w = t >> 6, wr = w >> 1, wc = w & 1;
    const int q = lane >> 4, l16 = lane & 15;

    f32x4 zero = {0.f, 0.f, 0.f, 0.f};
    f32x4 acc[4][4];
    #pragma unroll
    for (int mi = 0; mi < 4; mi++)
        #pragma unroll
        for (int ni = 0; ni < 4; ni++) acc[mi][ni] = zero;

    for (int k0i = ks * 32; k0i < ks * 32 + 32; k0i++) {
        const int k0 = k0i * 32;
        gl2lds16(rp + k0 + kga * 8, &Al[t * 8]);
        gl2lds16(rp + k0 + (kga + 2) * 8, &Al[(t + 256) * 8]);
        const unsigned short* ps = pb + (size_t)k0i * 4096;
        gl2lds16(ps + t * 8, &Bl[t * 8]);
        gl2lds16(ps + (t + 256) * 8, &Bl[(t + 256) * 8]);
        __syncthreads();

        s16x8 af[4], bf[4];
        #pragma unroll
        for (int mi = 0; mi < 4; mi++)
            af[mi] = *(const s16x8*)&Al[(q * 128 + wr * 64 + mi * 16 + l16) * 8];
        #pragma unroll
        for (int ni = 0; ni < 4; ni++)
            bf[ni] = *(const s16x8*)&Bl[(q * 128 + wc * 64 + ni * 16 + l16) * 8];
        #pragma unroll
        for (int mi = 0; mi < 4; mi++)
            #pragma unroll
            for (int ni = 0; ni < 4; ni++)
                acc[mi][ni] = MFMA16(af[mi], bf[ni], acc[mi][ni]);
        __syncthreads();
    }

    #pragma unroll
    for (int mi = 0; mi < 4; mi++)
        #pragma unroll
        for (int r = 0; r < 4; r++) {
            int row = rowb + wr * 64 + mi * 16 + q * 4 + r;
            int tok = wsi[WS_ROWTOK + row];
            if (tok < 0) continue;
            float sc = wsf[WS_ROWSC + row];
            #pragma unroll
            for (int ni = 0; ni < 4; ni++) {
                int col = ht * 128 + wc * 64 + ni * 16 + l16;
                atomicAdd(&out[(size_t)tok * H + col], acc[mi][ni][r] * sc);
            }
        }
}

extern "C" void kernel_launch(void* const* d_in, const int* in_sizes, int n_in,
                              void* d_out, int out_size, void* d_ws, size_t ws_size,
                              hipStream_t stream) {
    const float* hs     = (const float*)d_in[0];
    const float* logits = (const float*)d_in[1];
    const float* w1     = (const float*)d_in[2];
    const float* w2     = (const float*)d_in[3];
    float* out = (float*)d_out;
    int* wsi = (int*)d_ws;
    float* wsf = (float*)d_ws;
    unsigned short* zrow = (unsigned short*)((char*)d_ws + WSB_ZROW);
    unsigned short* hsb  = (unsigned short*)((char*)d_ws + WSB_HSB);
    unsigned short* act  = (unsigned short*)((char*)d_ws + WSB_ACT);
    unsigned short* pw1  = (unsigned short*)((char*)d_ws + WSB_PW1);
    unsigned short* pw2  = (unsigned short*)((char*)d_ws + WSB_PW2);

    hipMemsetAsync(d_ws, 0, 128, stream);
    hipMemsetAsync(d_out, 0, (size_t)out_size * sizeof(float), stream);

    router_kernel<<<(T + 255) / 256, 256, 0, stream>>>(logits, wsi, wsf);
    plan_kernel<<<1, 256, 0, stream>>>(wsi);
    scatter_kernel<<<(T + 255) / 256, 256, 0, stream>>>(wsi, wsf);
    prep_kernel<<<PW1_BLKS + HSB_BLKS, 256, 0, stream>>>(w1, pw1, hs, hsb);
    fc1_packw2_kernel<<<FC1_BLKS + PW2_BLKS, 256, 0, stream>>>(hsb, pw1, wsi, zrow, act, w2, pw2);
    fc2_kernel<<<dim3(8, MAXT, 2), 256, 0, stream>>>(act, pw2, wsi, wsf, out);
}

// Round 4
// 382.319 us; speedup vs baseline: 1.4038x; 1.0941x over previous
//
#include <hip/hip_runtime.h>
#include <hip/hip_bf16.h>

// Problem constants (AriaExperts): tokens=2048, hidden=1024, inter=2048, E=8, topk=2
constexpr int T = 2048;
constexpr int H = 1024;
constexpr int I = 2048;
constexpr int N2 = 2 * I;      // fc1 weight cols (proj|gate)
constexpr int RCAP = 5120;     // padded row capacity
constexpr int MAXT = 40;       // max 128-row tiles

// ws int-offset map (ints)
constexpr int WS_OFF = 16;                 // [16,25) expert row offsets (padded)
constexpr int WS_TEXP = 32;                // [32,72) tile -> expert
constexpr int WS_TOPKP = 4256;             // [4256,8352) token scales (float)
constexpr int WS_ROWTOK = 8352;            // [8352,13472) row -> token
constexpr int WS_TOKROW = 13472;           // [13472,17568) token -> 2 rows
// ws byte offsets
constexpr size_t WSB_ZROW = 114688;        // bf16 zero row, H elements
constexpr size_t WSB_HSB  = 131072;        // bf16 hidden_states [T][H] (4 MB)
constexpr size_t WSB_ACT  = 8u << 20;      // bf16 act [RCAP][I] (20 MB)
constexpr size_t WSB_PW1  = 32u << 20;     // packed bf16 w1 (64 MB); reused as eo[2][RCAP][H] fp32 (40 MB)
constexpr size_t WSB_PW2  = 96u << 20;     // packed bf16 w2 (32 MB) -> 128 MB ws

constexpr int PW1_BLKS = 8192;
constexpr int PW2_BLKS = 4096;
constexpr int HSB_BLKS = T * H / 2048;     // 1024
constexpr int FC1_BLKS = 32 * MAXT;        // 1280

typedef __attribute__((ext_vector_type(4))) float f32x4;
typedef __attribute__((ext_vector_type(8))) short s16x8;

__device__ __forceinline__ short f2bf(float f) {
    unsigned u = __float_as_uint(f);
    u += 0x7FFFu + ((u >> 16) & 1u);   // round-to-nearest-even
    return (short)(u >> 16);
}

#define MFMA16(a, b, c) __builtin_amdgcn_mfma_f32_16x16x32_bf16(a, b, c, 0, 0, 0)

__device__ __forceinline__ void gl2lds16(const void* g, void* l) {
    __builtin_amdgcn_global_load_lds(
        (const __attribute__((address_space(1))) void*)g,
        (__attribute__((address_space(3))) void*)l, 16, 0, 0);
}

// ---------------- routing: top2+softmax, histogram, prefix, scatter, inits (1 block) ----------------
__global__ __launch_bounds__(256) void routing_kernel(const float* __restrict__ logits,
                                                      int* __restrict__ wsi,
                                                      float* __restrict__ wsf) {
    __shared__ int cnt[8], base[9], fill[8];
    const int t = threadIdx.x;
    if (t < 8) { cnt[t] = 0; fill[t] = 0; }
    for (int r = t; r < RCAP; r += 256) wsi[WS_ROWTOK + r] = -1;
    unsigned short* zr = (unsigned short*)((char*)wsi + WSB_ZROW);
    for (int i = t; i < H; i += 256) zr[i] = 0;
    __syncthreads();

    int e0a[8], e1a[8];
    #pragma unroll
    for (int j = 0; j < 8; j++) {
        int tok = t * 8 + j;
        const float* l = logits + tok * 8;
        float v0 = -1e30f; int i0 = 0;
        #pragma unroll
        for (int i = 0; i < 8; i++) { float v = l[i]; if (v > v0) { v0 = v; i0 = i; } }
        float v1 = -1e30f; int i1 = 0;
        #pragma unroll
        for (int i = 0; i < 8; i++) { if (i == i0) continue; float v = l[i]; if (v > v1) { v1 = v; i1 = i; } }
        float ex = __expf(v1 - v0);
        float inv = 1.f / (1.f + ex);
        wsf[WS_TOPKP + tok * 2] = inv;
        wsf[WS_TOPKP + tok * 2 + 1] = ex * inv;
        e0a[j] = i0; e1a[j] = i1;
        atomicAdd(&cnt[i0], 1);
        atomicAdd(&cnt[i1], 1);
    }
    __syncthreads();
    if (t == 0) {
        int acc = 0;
        for (int e = 0; e < 8; e++) { base[e] = acc; acc += (cnt[e] + 127) & ~127; }
        base[8] = acc;
        for (int e = 0; e < 9; e++) wsi[WS_OFF + e] = base[e];
    }
    __syncthreads();
    for (int tt = t; tt < MAXT; tt += 256) {
        int rb = tt * 128, ex = 0;
        for (int e = 0; e < 8; e++)
            if (rb >= base[e] && rb < base[e + 1]) ex = e;
        wsi[WS_TEXP + tt] = ex;
    }
    #pragma unroll
    for (int j = 0; j < 8; j++) {
        int tok = t * 8 + j;
        int ee[2] = {e0a[j], e1a[j]};
        #pragma unroll
        for (int k = 0; k < 2; k++) {
            int e = ee[k];
            int slot = atomicAdd(&fill[e], 1);
            int r = base[e] + slot;
            wsi[WS_ROWTOK + r] = tok;
            wsi[WS_TOKROW + tok * 2 + k] = r;
        }
    }
}

// ---------------- prep: pack w1 (interleaved 32p|32g), pack w2, hs->bf16 ----------------
// pw1: [e][ct:32][k0i:32] x 4096 = [kg:4][n:128][kk:8]; tile col n: sub=n>>5,
//      global col = (sub&1 ? I : 0) + ct*64 + (sub>>1)*32 + (n&31)
// pw2: [e][ht:8][k0i:64] x 4096 = [kg:4][n:128][kk:8]
__global__ __launch_bounds__(256) void prep_kernel(
    const float* __restrict__ w1, unsigned short* __restrict__ pw1,
    const float* __restrict__ w2, unsigned short* __restrict__ pw2,
    const float* __restrict__ hs, unsigned short* __restrict__ hsb) {
    const int t = threadIdx.x;
    if (blockIdx.x < PW1_BLKS) {
        int b = blockIdx.x;                 // ((e*32+ct)*32)+k0i
        int k0i = b & 31, ct = (b >> 5) & 31, e = b >> 10;
        const float* src = w1 + (size_t)e * H * N2;
        unsigned short* dst = pw1 + (size_t)b * 4096;
        #pragma unroll
        for (int j = 0; j < 2; j++) {
            int g = t + j * 256;
            int kg = g >> 7, n = g & 127;
            int sub = n >> 5, within = n & 31;
            int col = ((sub & 1) ? I : 0) + ct * 64 + (sub >> 1) * 32 + within;
            int kbase = k0i * 32 + kg * 8;
            const float* sp = src + (size_t)kbase * N2 + col;
            s16x8 s;
            #pragma unroll
            for (int kk = 0; kk < 8; kk++) s[kk] = f2bf(sp[(size_t)kk * N2]);
            *(s16x8*)(dst + g * 8) = s;
        }
    } else if (blockIdx.x < PW1_BLKS + PW2_BLKS) {
        int b = blockIdx.x - PW1_BLKS;      // ((e*8+ht)*64)+k0i
        int k0i = b & 63, ht = (b >> 6) & 7, e = b >> 9;
        const float* src = w2 + (size_t)e * I * H;
        unsigned short* dst = pw2 + (size_t)b * 4096;
        #pragma unroll
        for (int j = 0; j < 2; j++) {
            int g = t + j * 256;
            int kg = g >> 7, n = g & 127;
            int col = ht * 128 + n;
            int kbase = k0i * 32 + kg * 8;
            const float* sp = src + (size_t)kbase * H + col;
            s16x8 s;
            #pragma unroll
            for (int kk = 0; kk < 8; kk++) s[kk] = f2bf(sp[(size_t)kk * H]);
            *(s16x8*)(dst + g * 8) = s;
        }
    } else {
        int i = ((blockIdx.x - PW1_BLKS - PW2_BLKS) * 256 + t) * 8;
        f32x4 a = *(const f32x4*)(hs + i);
        f32x4 b = *(const f32x4*)(hs + i + 4);
        s16x8 s = {f2bf(a[0]), f2bf(a[1]), f2bf(a[2]), f2bf(a[3]),
                   f2bf(b[0]), f2bf(b[1]), f2bf(b[2]), f2bf(b[3])};
        *(s16x8*)(hsb + i) = s;
    }
}

// ---------------- fc1 (128x128, BK=32) + SwiGLU ----------------
__global__ __launch_bounds__(256, 2) void fc1_kernel(
    const unsigned short* __restrict__ hsb, const unsigned short* __restrict__ pw1,
    const int* __restrict__ wsi, const unsigned short* __restrict__ zrow,
    unsigned short* __restrict__ act) {
    __shared__ __align__(16) unsigned short Al[512 * 8];    // [kg:4][m:128][8]
    __shared__ __align__(16) unsigned short Bl[512 * 8];    // [kg:4][n:128][8]
    const int t = threadIdx.x;
    const int ct = blockIdx.x & 31, rt = blockIdx.x >> 5;
    const int rowb = rt * 128;
    if (rowb >= wsi[WS_OFF + 8]) return;
    const int e = wsi[WS_TEXP + rt];
    const unsigned short* pb = pw1 + (size_t)((e * 32 + ct) * 32) * 4096;

    const int m = t & 127;
    const int tok = wsi[WS_ROWTOK + rowb + m];
    const unsigned short* rp = (tok >= 0) ? (hsb + (size_t)tok * H) : zrow;
    const int kga = t >> 7;

    const int lane = t & 63, w = t >> 6, wr = w >> 1, wc = w & 1;
    const int q = lane >> 4, l16 = lane & 15;

    f32x4 zero = {0.f, 0.f, 0.f, 0.f};
    f32x4 acc[4][4];
    #pragma unroll
    for (int mi = 0; mi < 4; mi++)
        #pragma unroll
        for (int ni = 0; ni < 4; ni++) acc[mi][ni] = zero;

    for (int k0i = 0; k0i < 32; k0i++) {
        const int k0 = k0i * 32;
        gl2lds16(rp + k0 + kga * 8, &Al[t * 8]);
        gl2lds16(rp + k0 + (kga + 2) * 8, &Al[(t + 256) * 8]);
        const unsigned short* ps = pb + (size_t)k0i * 4096;
        gl2lds16(ps + t * 8, &Bl[t * 8]);
        gl2lds16(ps + (t + 256) * 8, &Bl[(t + 256) * 8]);
        __syncthreads();

        s16x8 af[4], bf[4];
        #pragma unroll
        for (int mi = 0; mi < 4; mi++)
            af[mi] = *(const s16x8*)&Al[(q * 128 + wr * 64 + mi * 16 + l16) * 8];
        #pragma unroll
        for (int ni = 0; ni < 4; ni++)
            bf[ni] = *(const s16x8*)&Bl[(q * 128 + wc * 64 + ni * 16 + l16) * 8];
        #pragma unroll
        for (int mi = 0; mi < 4; mi++)
            #pragma unroll
            for (int ni = 0; ni < 4; ni++)
                acc[mi][ni] = MFMA16(af[mi], bf[ni], acc[mi][ni]);
        __syncthreads();
    }

    // epilogue: wave cols = 32 proj + 32 gate (ni 0,1 = proj; ni 2,3 = matching gate)
    #pragma unroll
    for (int mi = 0; mi < 4; mi++)
        #pragma unroll
        for (int r = 0; r < 4; r++) {
            int row = rowb + wr * 64 + mi * 16 + q * 4 + r;
            #pragma unroll
            for (int ni = 0; ni < 2; ni++) {
                int col = ct * 64 + wc * 32 + ni * 16 + l16;
                float p = acc[mi][ni][r], g = acc[mi][ni + 2][r];
                float val = p * g / (1.f + __expf(-p));
                act[(size_t)row * I + col] = (unsigned short)f2bf(val);
            }
        }
}

// ---------------- fc2 (128x128, BK=32, K-split x2) -> eo partials, no atomics ----------------
__global__ __launch_bounds__(256, 2) void fc2_kernel(
    const unsigned short* __restrict__ act, const unsigned short* __restrict__ pw2,
    const int* __restrict__ wsi, float* __restrict__ eo) {
    __shared__ __align__(16) unsigned short Al[512 * 8];
    __shared__ __align__(16) unsigned short Bl[512 * 8];
    const int t = threadIdx.x;
    const int ht = blockIdx.x, rt = blockIdx.y, ks = blockIdx.z;
    const int rowb = rt * 128;
    if (rowb >= wsi[WS_OFF + 8]) return;
    const int e = wsi[WS_TEXP + rt];
    const unsigned short* pb = pw2 + (size_t)((e * 8 + ht) * 64) * 4096;

    const int m = t & 127;
    const unsigned short* rp = act + (size_t)(rowb + m) * I;
    const int kga = t >> 7;

    const int lane = t & 63, w = t >> 6, wr = w >> 1, wc = w & 1;
    const int q = lane >> 4, l16 = lane & 15;

    f32x4 zero = {0.f, 0.f, 0.f, 0.f};
    f32x4 acc[4][4];
    #pragma unroll
    for (int mi = 0; mi < 4; mi++)
        #pragma unroll
        for (int ni = 0; ni < 4; ni++) acc[mi][ni] = zero;

    for (int k0i = ks * 32; k0i < ks * 32 + 32; k0i++) {
        const int k0 = k0i * 32;
        gl2lds16(rp + k0 + kga * 8, &Al[t * 8]);
        gl2lds16(rp + k0 + (kga + 2) * 8, &Al[(t + 256) * 8]);
        const unsigned short* ps = pb + (size_t)k0i * 4096;
        gl2lds16(ps + t * 8, &Bl[t * 8]);
        gl2lds16(ps + (t + 256) * 8, &Bl[(t + 256) * 8]);
        __syncthreads();

        s16x8 af[4], bf[4];
        #pragma unroll
        for (int mi = 0; mi < 4; mi++)
            af[mi] = *(const s16x8*)&Al[(q * 128 + wr * 64 + mi * 16 + l16) * 8];
        #pragma unroll
        for (int ni = 0; ni < 4; ni++)
            bf[ni] = *(const s16x8*)&Bl[(q * 128 + wc * 64 + ni * 16 + l16) * 8];
        #pragma unroll
        for (int mi = 0; mi < 4; mi++)
            #pragma unroll
            for (int ni = 0; ni < 4; ni++)
                acc[mi][ni] = MFMA16(af[mi], bf[ni], acc[mi][ni]);
        __syncthreads();
    }

    float* ed = eo + (size_t)ks * RCAP * H;
    #pragma unroll
    for (int mi = 0; mi < 4; mi++)
        #pragma unroll
        for (int r = 0; r < 4; r++) {
            int row = rowb + wr * 64 + mi * 16 + q * 4 + r;
            #pragma unroll
            for (int ni = 0; ni < 4; ni++) {
                int col = ht * 128 + wc * 64 + ni * 16 + l16;
                ed[(size_t)row * H + col] = acc[mi][ni][r];
            }
        }
}

// ---------------- combine: out[tok] = s0*(eo0[r0]+eo1[r0]) + s1*(eo0[r1]+eo1[r1]) ----------------
__global__ __launch_bounds__(256) void combine_kernel(
    const float* __restrict__ eo, const int* __restrict__ wsi,
    const float* __restrict__ wsf, float* __restrict__ out) {
    const int tok = blockIdx.x;
    const int r0 = wsi[WS_TOKROW + tok * 2], r1 = wsi[WS_TOKROW + tok * 2 + 1];
    const float s0 = wsf[WS_TOPKP + tok * 2], s1 = wsf[WS_TOPKP + tok * 2 + 1];
    const float* a0 = eo + (size_t)r0 * H;
    const float* a1 = eo + (size_t)RCAP * H + (size_t)r0 * H;
    const float* b0 = eo + (size_t)r1 * H;
    const float* b1 = eo + (size_t)RCAP * H + (size_t)r1 * H;
    const int c = threadIdx.x * 4;
    f32x4 va0 = *(const f32x4*)(a0 + c), va1 = *(const f32x4*)(a1 + c);
    f32x4 vb0 = *(const f32x4*)(b0 + c), vb1 = *(const f32x4*)(b1 + c);
    f32x4 r;
    #pragma unroll
    for (int i = 0; i < 4; i++) r[i] = s0 * (va0[i] + va1[i]) + s1 * (vb0[i] + vb1[i]);
    *(f32x4*)(out + (size_t)tok * H + c) = r;
}

extern "C" void kernel_launch(void* const* d_in, const int* in_sizes, int n_in,
                              void* d_out, int out_size, void* d_ws, size_t ws_size,
                              hipStream_t stream) {
    const float* hs     = (const float*)d_in[0];
    const float* logits = (const float*)d_in[1];
    const float* w1     = (const float*)d_in[2];
    const float* w2     = (const float*)d_in[3];
    float* out = (float*)d_out;
    int* wsi = (int*)d_ws;
    float* wsf = (float*)d_ws;
    unsigned short* zrow = (unsigned short*)((char*)d_ws + WSB_ZROW);
    unsigned short* hsb  = (unsigned short*)((char*)d_ws + WSB_HSB);
    unsigned short* act  = (unsigned short*)((char*)d_ws + WSB_ACT);
    unsigned short* pw1  = (unsigned short*)((char*)d_ws + WSB_PW1);
    unsigned short* pw2  = (unsigned short*)((char*)d_ws + WSB_PW2);
    float* eo = (float*)((char*)d_ws + WSB_PW1);   // aliases pw1 (consumed by fc1 before fc2 runs)

    routing_kernel<<<1, 256, 0, stream>>>(logits, wsi, wsf);
    prep_kernel<<<PW1_BLKS + PW2_BLKS + HSB_BLKS, 256, 0, stream>>>(w1, pw1, w2, pw2, hs, hsb);
    fc1_kernel<<<FC1_BLKS, 256, 0, stream>>>(hsb, pw1, wsi, zrow, act);
    fc2_kernel<<<dim3(8, MAXT, 2), 256, 0, stream>>>(act, pw2, wsi, eo);
    combine_kernel<<<T, 256, 0, stream>>>(eo, wsi, wsf, out);
}